// Round 9
// baseline (198.199 us; speedup 1.0000x reference)
//
#include <hip/hip_runtime.h>
#include <stdint.h>

typedef __attribute__((ext_vector_type(8))) short  bf16x8;
typedef __attribute__((ext_vector_type(4))) float  f32x4;
typedef __attribute__((ext_vector_type(4))) int    int4v;
typedef __attribute__((ext_vector_type(4))) float  float4v;
typedef __attribute__((ext_vector_type(4))) unsigned int uint4v;
typedef __attribute__((ext_vector_type(2))) unsigned int uint2v;

#define NN   8192   // nodes
#define DIN  512
#define DOUT 256
#define NW   (NN / 32)   // 256 dwords of bits per row

// k_agg geometry: block tile 128m x 128n (4 waves of 64x64), KSPLIT=8
#define BM2     128
#define BN2     128
#define KSPLIT2 8
#define KS2     (NN / KSPLIT2)  // 1024
#define BK2     64
#define NTK     (KS2 / BK2)     // 16

#define MFMA16(a, b, c) __builtin_amdgcn_mfma_f32_16x16x32_bf16((a), (b), (c), 0, 0, 0)

__device__ __forceinline__ unsigned short f2bf(float f) {
  unsigned u = __float_as_uint(f);
  return (unsigned short)((u + 0x7FFFu + ((u >> 16) & 1u)) >> 16);
}

// ---------------------------------------------------------------------------
// Kernel 0: Wt[n][c] = bf16(W[c][n]).  W: [512][256] f32 -> Wt: [256][512] bf16
// ---------------------------------------------------------------------------
__global__ void k_wt(const float* __restrict__ W, unsigned short* __restrict__ Wt) {
  int n = blockIdx.x; // 0..255
  for (int c = threadIdx.x; c < DIN; c += blockDim.x)
    Wt[n * DIN + c] = f2bf(W[c * DOUT + n]);
}

// ---------------------------------------------------------------------------
// Kernel 1: xw_t[n][m] = sum_c x[m][c] * W[c][n]   (bf16 out, transposed)
// ---------------------------------------------------------------------------
__global__ __launch_bounds__(256) void k_xwt(const float* __restrict__ x,
                                             const unsigned short* __restrict__ Wt,
                                             unsigned short* __restrict__ xw_t) {
  const int mb = blockIdx.x >> 1, nb = blockIdx.x & 1;
  const int tid = threadIdx.x;
  const int w = tid >> 6, l = tid & 63;
  const int wm = w >> 1, wn = w & 1;
  const int lr = l & 15, lg = l >> 4;
  const int m_base = mb * 128 + wm * 64;
  const int n_base = nb * 128 + wn * 64;

  f32x4 acc[4][4];
  for (int i = 0; i < 4; ++i)
    for (int j = 0; j < 4; ++j) acc[i][j] = (f32x4)0.0f;

  for (int c0 = 0; c0 < DIN; c0 += 32) {
    const int c = c0 + lg * 8;
    bf16x8 af[4], bfv[4];
#pragma unroll
    for (int mt = 0; mt < 4; ++mt) {
      const float* xp = x + (size_t)(m_base + mt * 16 + lr) * DIN + c;
      float4v x0 = *reinterpret_cast<const float4v*>(xp);
      float4v x1 = *reinterpret_cast<const float4v*>(xp + 4);
      bf16x8 a;
#pragma unroll
      for (int j = 0; j < 4; ++j) {
        a[j]     = (short)f2bf(x0[j]);
        a[4 + j] = (short)f2bf(x1[j]);
      }
      af[mt] = a;
    }
#pragma unroll
    for (int nt = 0; nt < 4; ++nt)
      bfv[nt] = *reinterpret_cast<const bf16x8*>(Wt + (size_t)(n_base + nt * 16 + lr) * DIN + c);
#pragma unroll
    for (int mt = 0; mt < 4; ++mt)
#pragma unroll
      for (int nt = 0; nt < 4; ++nt)
        acc[mt][nt] = MFMA16(af[mt], bfv[nt], acc[mt][nt]);
  }

#pragma unroll
  for (int nt = 0; nt < 4; ++nt) {
    const int n = n_base + nt * 16 + lr;
#pragma unroll
    for (int mt = 0; mt < 4; ++mt) {
      const int m = m_base + mt * 16 + lg * 4;
      unsigned short b0 = f2bf(acc[mt][nt][0]), b1 = f2bf(acc[mt][nt][1]);
      unsigned short b2 = f2bf(acc[mt][nt][2]), b3 = f2bf(acc[mt][nt][3]);
      uint2v p;
      p[0] = (unsigned)b0 | ((unsigned)b1 << 16);
      p[1] = (unsigned)b2 | ((unsigned)b3 << 16);
      *reinterpret_cast<uint2v*>(xw_t + (size_t)n * NN + m) = p;
    }
  }
}

// ---------------------------------------------------------------------------
// Kernel 2: pack adj -> bits + deg via wave ballot (unchanged from r7/r8).
// ---------------------------------------------------------------------------
__global__ __launch_bounds__(256) void k_pack(const int* __restrict__ adj,
                                              unsigned int* __restrict__ bits,
                                              int* __restrict__ deg) {
  __shared__ int wsum[4];
  const int tid = threadIdx.x;
  const int w = tid >> 6, l = tid & 63;
  const int row = blockIdx.x;
  const int* src = adj + (size_t)row * NN + w * 2048 + l;
  unsigned long long* bdst =
      reinterpret_cast<unsigned long long*>(bits + (size_t)row * NW + w * 64);

  int cnt = 0;
#pragma unroll
  for (int it = 0; it < 32; it += 8) {
    unsigned long long b[8];
#pragma unroll
    for (int u = 0; u < 8; ++u)
      b[u] = __ballot(src[(it + u) * 64] != 0);
#pragma unroll
    for (int u = 0; u < 8; ++u) {
      if (l == 0) bdst[it + u] = b[u];
      cnt += (int)__popcll(b[u]);
    }
  }

  if (l == 0) wsum[w] = cnt;
  __syncthreads();
  if (tid == 0) deg[row] = wsum[0] + wsum[1] + wsum[2] + wsum[3];
}

// ---------------------------------------------------------------------------
// Kernel 3: split-K partial  outp[ks] = A_bits[rows,kslice] * xw[kslice,:]
// BARRIER-FREE, LDS-FREE. Block = 256 thr = 4 waves (2 wm x 2 wn), block tile
// 128m x 128n; grid 1024 = 64 rb x 2 nb x 8 ks (~3-4 blocks/CU). ks=bid&7
// XCD-pins the 512 KB B slice into local L2; waves load B fragments DIRECTLY
// from L2 (b128), register-double-buffered one K-tile ahead via unroll-by-2
// role swap. A-bits (L2-hot) likewise. Issue order: B(t+1), A(t+1), then
// COMPUTE(t) on older regs -> compiler emits counted vmcnt, no drains, no
// __syncthreads anywhere. Exclusive partial stores.
// ---------------------------------------------------------------------------
__global__ __launch_bounds__(256, 3) void k_agg(const unsigned int* __restrict__ bits,
                                                const unsigned short* __restrict__ xw_t,
                                                float* __restrict__ outp) {
  const int tid = threadIdx.x;
  const int w = tid >> 6, l = tid & 63;
  const int lr = l & 15, lg = l >> 4;
  const int wm = w >> 1, wn = w & 1;

  const int bid = blockIdx.x;
  const int ks = bid & 7;          // XCD pin
  const int rem = bid >> 3;        // 0..127
  const int nb = rem & 1;
  const int rb = rem >> 1;         // 0..63
  const int row0 = rb * BM2;
  const int kbase = ks * KS2;

  const unsigned int* gA = bits + (size_t)(row0 + wm * 64 + lr) * NW + (kbase >> 5);
  const unsigned short* bP = xw_t + (size_t)(nb * 128 + wn * 64 + lr) * NN + kbase + lg * 8;

  f32x4 acc[4][4]; // [mf][nf]
#pragma unroll
  for (int i = 0; i < 4; ++i)
#pragma unroll
    for (int j = 0; j < 4; ++j) acc[i][j] = (f32x4)0.0f;

  bf16x8 Bc[8], Bn[8];   // [nf*2+kf], statically indexed
  uint2v Ab[4], An[4];

#define LOADB(B, t) do {                                                       \
    _Pragma("unroll")                                                          \
    for (int nf_ = 0; nf_ < 4; ++nf_) {                                        \
      B[nf_ * 2 + 0] = *reinterpret_cast<const bf16x8*>(bP + (size_t)nf_ * 16 * NN + (t) * BK2);      \
      B[nf_ * 2 + 1] = *reinterpret_cast<const bf16x8*>(bP + (size_t)nf_ * 16 * NN + (t) * BK2 + 32); \
    }                                                                          \
  } while (0)

#define LOADA(t, arr) do {                                                     \
    _Pragma("unroll")                                                          \
    for (int mf_ = 0; mf_ < 4; ++mf_)                                          \
      arr[mf_] = *reinterpret_cast<const uint2v*>(gA + (size_t)mf_ * 16 * NW + 2 * (t)); \
  } while (0)

#define COMPUTE(Aa, B) do {                                                    \
    _Pragma("unroll")                                                          \
    for (int kf_ = 0; kf_ < 2; ++kf_) {                                        \
      _Pragma("unroll")                                                        \
      for (int mf_ = 0; mf_ < 4; ++mf_) {                                      \
        const unsigned a32_ = Aa[mf_][kf_];                                    \
        uint4v q_;                                                             \
        _Pragma("unroll")                                                      \
        for (int j_ = 0; j_ < 4; ++j_) {                                       \
          unsigned b2_ = (a32_ >> (lg * 8 + 2 * j_)) & 3u;                     \
          q_[j_] = ((b2_ | (b2_ << 15)) & 0x10001u) * 0x3F80u;                 \
        }                                                                      \
        const bf16x8 af_ = *reinterpret_cast<const bf16x8*>(&q_);              \
        acc[mf_][0] = MFMA16(af_, B[0 * 2 + kf_], acc[mf_][0]);                \
        acc[mf_][1] = MFMA16(af_, B[1 * 2 + kf_], acc[mf_][1]);                \
        acc[mf_][2] = MFMA16(af_, B[2 * 2 + kf_], acc[mf_][2]);                \
        acc[mf_][3] = MFMA16(af_, B[3 * 2 + kf_], acc[mf_][3]);                \
      }                                                                        \
    }                                                                          \
  } while (0)

  // prologue: tile 0 into the "current" regs
  LOADB(Bc, 0);
  LOADA(0, Ab);

  for (int t = 0; t < NTK; t += 2) {
    LOADB(Bn, t + 1);                 // issue next tile first (newer than Bc/Ab)
    LOADA(t + 1, An);
    COMPUTE(Ab, Bc);                  // waits only on older Bc/Ab
    if (t + 2 < NTK) {
      LOADB(Bc, t + 2);
      LOADA(t + 2, Ab);
    }
    COMPUTE(An, Bn);
  }
#undef LOADB
#undef LOADA
#undef COMPUTE

  // exclusive partial store
  float* po = outp + (size_t)ks * NN * DOUT;
#pragma unroll
  for (int mf = 0; mf < 4; ++mf)
#pragma unroll
    for (int nf = 0; nf < 4; ++nf)
#pragma unroll
      for (int r = 0; r < 4; ++r) {
        const int row = row0 + wm * 64 + mf * 16 + lg * 4 + r;
        const int col = nb * 128 + wn * 64 + nf * 16 + lr;
        po[(size_t)row * DOUT + col] = acc[mf][nf][r];
      }
}

// ---------------------------------------------------------------------------
// Kernel 4: out = (sum_ks outp[ks]) / deg
// ---------------------------------------------------------------------------
__global__ __launch_bounds__(256) void k_div(const float* __restrict__ outp,
                                             const int* __restrict__ deg,
                                             float* __restrict__ out) {
  const int idx = blockIdx.x * 256 + threadIdx.x;
  const size_t i4 = (size_t)idx * 4;
  const int row = (int)(i4 >> 8); // DOUT=256
  float4v s = *reinterpret_cast<const float4v*>(outp + i4);
#pragma unroll
  for (int p = 1; p < KSPLIT2; ++p) {
    float4v v = *reinterpret_cast<const float4v*>(outp + (size_t)p * NN * DOUT + i4);
    s[0] += v[0]; s[1] += v[1]; s[2] += v[2]; s[3] += v[3];
  }
  const float sc = 1.0f / (float)deg[row];
  s[0] *= sc; s[1] *= sc; s[2] *= sc; s[3] *= sc;
  *reinterpret_cast<float4v*>(out + i4) = s;
}

// ---------------------------------------------------------------------------
extern "C" void kernel_launch(void* const* d_in, const int* in_sizes, int n_in,
                              void* d_out, int out_size, void* d_ws, size_t ws_size,
                              hipStream_t stream) {
  const float* x   = (const float*)d_in[0]; // [8192][512] f32
  const int*   adj = (const int*)d_in[1];   // [8192][8192] i32 (0/1)
  const float* W   = (const float*)d_in[2]; // [512][256] f32
  float* out = (float*)d_out;               // [8192][256] f32

  char* ws = (char*)d_ws;
  unsigned short* xw_t = (unsigned short*)ws;                               // 4 MB
  unsigned short* Wt   = (unsigned short*)(ws + (size_t)4 * 1024 * 1024);   // 256 KB
  int*            deg  = (int*)(ws + (size_t)4 * 1024 * 1024 + 512 * 1024); // 32 KB
  unsigned int*   bits = (unsigned int*)(ws + (size_t)5 * 1024 * 1024);     // 8 MB
  float*          outp = (float*)(ws + (size_t)16 * 1024 * 1024);           // 64 MB

  k_wt<<<256, 128, 0, stream>>>(W, Wt);
  k_xwt<<<128, 256, 0, stream>>>(x, Wt, xw_t);
  k_pack<<<NN, 256, 0, stream>>>(adj, bits, deg);
  k_agg<<<(NN / BM2) * 2 * KSPLIT2, 256, 0, stream>>>(bits, xw_t, outp);
  k_div<<<(NN * DOUT) / (256 * 4), 256, 0, stream>>>(outp, deg, out);
}